// Round 4
// baseline (1054.701 us; speedup 1.0000x reference)
//
#include <hip/hip_runtime.h>
#include <hip/hip_bf16.h>
#include <cfloat>
#include <cmath>

// Problem constants
#define H_DIM 768
#define IDX_D 64
#define KTOP 10
#define R_HEADS 12
#define READ_K 100
#define MD 64
#define WK 100
#define INTER 3072
#define N_NODES 50000
#define B_SZ 4
#define E_SZ 128
#define BE 512            // B*E
#define SLOTS 110         // KTOP + READ_K
#define HASH_SZ 2048
#define HASH_MASK 2047

// ---------------------------------------------------------------------------
// small utility kernels
// ---------------------------------------------------------------------------
__global__ void zero_loss_kernel(float* p) {
    if (threadIdx.x == 0 && blockIdx.x == 0) *p = 0.f;
}
__global__ void write_loss_kernel(const float* p, float* out) {
    if (threadIdx.x == 0 && blockIdx.x == 0) out[0] = *p / 65536.f;  // / (B*E*E)
}

// ---------------------------------------------------------------------------
// f32 GEMM, register-prefetch double-buffered LDS. Per-output FMA order is
// k-ascending with the same micro-tile as the harness-verified baseline ->
// bitwise-identical results (used for q_idx, which feeds discrete top-k).
// C[M,N] = A[M,K] @ B[K,N] + bias[N], optional exact GELU.
// ---------------------------------------------------------------------------
__global__ __launch_bounds__(256) void gemm_kernel(
    const float* __restrict__ A, const float* __restrict__ Bm,
    const float* __restrict__ bias, float* __restrict__ C,
    int M, int N, int K, int act)
{
    __shared__ float As[2][16][65];
    __shared__ float Bs[2][16][65];
    const int tid = threadIdx.x;
    const int tx = tid & 15, ty = tid >> 4;
    const int m0 = blockIdx.y * 64, n0 = blockIdx.x * 64;

    const int aty = tid >> 4, atx = tid & 15;   // A staging: rows aty+16j, col atx
    const int bky = tid >> 6, bnx = tid & 63;   // B staging: rows bky+4j, col bnx

    float acc[4][4] = {};
    float av[4], bv[4];

    auto stage = [&](int k0) {
        #pragma unroll
        for (int j = 0; j < 4; ++j)
            av[j] = A[(size_t)(m0 + aty + 16 * j) * K + k0 + atx];
        #pragma unroll
        for (int j = 0; j < 4; ++j)
            bv[j] = Bm[(size_t)(k0 + bky + 4 * j) * N + n0 + bnx];
    };
    auto commit = [&](int buf) {
        #pragma unroll
        for (int j = 0; j < 4; ++j) As[buf][atx][aty + 16 * j] = av[j];
        #pragma unroll
        for (int j = 0; j < 4; ++j) Bs[buf][bky + 4 * j][bnx] = bv[j];
    };
    auto compute = [&](int buf) {
        #pragma unroll
        for (int kk = 0; kk < 16; ++kk) {
            float a4[4], b4[4];
            #pragma unroll
            for (int u = 0; u < 4; ++u) a4[u] = As[buf][kk][ty * 4 + u];
            #pragma unroll
            for (int v = 0; v < 4; ++v) b4[v] = Bs[buf][kk][tx * 4 + v];
            #pragma unroll
            for (int u = 0; u < 4; ++u)
                #pragma unroll
                for (int v = 0; v < 4; ++v) acc[u][v] += a4[u] * b4[v];
        }
    };

    stage(0);
    commit(0);
    __syncthreads();
    int buf = 0;
    for (int k0 = 16; k0 < K; k0 += 16) {
        stage(k0);          // next tile's global loads in flight...
        compute(buf);       // ...while FMAs consume the current tile
        commit(buf ^ 1);
        __syncthreads();
        buf ^= 1;
    }
    compute(buf);

    #pragma unroll
    for (int u = 0; u < 4; ++u) {
        int m = m0 + ty * 4 + u;
        #pragma unroll
        for (int v = 0; v < 4; ++v) {
            int n = n0 + tx * 4 + v;
            float x = acc[u][v] + bias[n];
            if (act) x = 0.5f * x * (1.f + erff(x * 0.70710678118654752f));
            C[(size_t)m * N + n] = x;
        }
    }
}

// ---------------------------------------------------------------------------
// split-bf16 MFMA GEMM: C = A@B (+bias)(+gelu), fp32 in/out, ~1e-5 rel error.
// A = Ahi + Alo, B = Bhi + Blo (bf16 RNE hi + bf16 residual lo);
// C ~= Ahi*Bhi + Ahi*Blo + Alo*Bhi  (lo*lo term ~2^-18 rel, dropped).
// 128x128 tile, 4 waves (2x2), mfma_f32_16x16x32_bf16, K-step 32.
// LDS is fragment-ordered: per 16x32 subtile, lane l owns u32s [l*4, l*4+4)
// -> ds_read_b128 conflict-free. Register double-buffer on staging.
// Split-K via blockIdx.z (chunk Kc, partial -> C + z*M*N, bias must be null).
// Fragment layouts (guide §3, m89-verified family; operand type short8 per
// the guide's compile-verified example):
//   A: lane 16g+r holds A[r][8g+j], j=0..7   (u32 slot s = elems 2s,2s+1)
//   B: lane 16g+c holds B[8g+j][c]
//   D: col = lane&15, row = 4*(lane>>4) + reg
// ---------------------------------------------------------------------------
typedef short bf16x8 __attribute__((ext_vector_type(8)));   // 8 bf16 in 4 VGPRs
typedef float f32x4 __attribute__((ext_vector_type(4)));
typedef unsigned int u32x4 __attribute__((ext_vector_type(4)));

__device__ inline unsigned f2bf(float x) {          // f32 -> bf16 bits (RNE)
    unsigned u = __float_as_uint(x);
    return (u + 0x7FFFu + ((u >> 16) & 1u)) >> 16;
}
__device__ inline float bfval(unsigned b) { return __uint_as_float(b << 16); }

__global__ __launch_bounds__(256) void gemm_mfma_kernel(
    const float* __restrict__ A, const float* __restrict__ Bm,
    const float* __restrict__ bias, float* __restrict__ C,
    int M, int N, int Kc, int lda, int act)
{
    // [buf][op: Ah,Al,Bh,Bl][8 subtiles * 256 u32] = 64 KiB
    __shared__ __align__(16) unsigned int lds[2][4][2048];

    const int tid = threadIdx.x;
    const int lane = tid & 63;
    const int w = tid >> 6, wr = w >> 1, wc = w & 1;
    const int m0 = blockIdx.y * 128, n0 = blockIdx.x * 128;
    const int kbase = blockIdx.z * Kc;
    float* __restrict__ Cp = C + (size_t)blockIdx.z * M * N;

    f32x4 acc[4][4] = {};
    unsigned apk[2][8];   // staged A packs [hi/lo][item]
    unsigned bpk[2][8];   // staged B packs [hi/lo][item]

    auto stage = [&](int k0) {
        #pragma unroll
        for (int it = 0; it < 8; ++it) {
            int idx = it * 256 + tid;
            int r = idx >> 4, p = idx & 15;           // row r, k-pair p
            const float2 v = *(const float2*)(A + (size_t)(m0 + r) * lda + kbase + k0 + 2 * p);
            unsigned h0 = f2bf(v.x), h1 = f2bf(v.y);
            apk[0][it] = h0 | (h1 << 16);
            apk[1][it] = f2bf(v.x - bfval(h0)) | (f2bf(v.y - bfval(h1)) << 16);
        }
        #pragma unroll
        for (int it = 0; it < 4; ++it) {
            int idx = it * 256 + tid;
            int cp = idx & 63, kp = idx >> 6;         // col-pair cp, k-pair kp
            const float* bp = Bm + (size_t)(kbase + k0 + 2 * kp) * N + n0 + 2 * cp;
            const float2 e = *(const float2*)bp;      // row k=2kp   : cols c,c+1
            const float2 o = *(const float2*)(bp + N);// row k=2kp+1 : cols c,c+1
            unsigned he0 = f2bf(e.x), ho0 = f2bf(o.x);
            unsigned he1 = f2bf(e.y), ho1 = f2bf(o.y);
            bpk[0][it * 2 + 0] = he0 | (ho0 << 16);   // col c:   (k even lo16, k odd hi16)
            bpk[1][it * 2 + 0] = f2bf(e.x - bfval(he0)) | (f2bf(o.x - bfval(ho0)) << 16);
            bpk[0][it * 2 + 1] = he1 | (ho1 << 16);   // col c+1
            bpk[1][it * 2 + 1] = f2bf(e.y - bfval(he1)) | (f2bf(o.y - bfval(ho1)) << 16);
        }
    };

    auto commit = [&](int buf) {
        #pragma unroll
        for (int it = 0; it < 8; ++it) {
            int idx = it * 256 + tid;
            int r = idx >> 4, p = idx & 15;
            // subtile r>>4; lane 16*(p>>2) + (r&15); u32 slot p&3
            int off = ((r >> 4) * 256) + ((p >> 2) * 64) + ((r & 15) * 4) + (p & 3);
            lds[buf][0][off] = apk[0][it];
            lds[buf][1][off] = apk[1][it];
        }
        #pragma unroll
        for (int it = 0; it < 4; ++it) {
            int idx = it * 256 + tid;
            int cp = idx & 63, kp = idx >> 6;
            int c = 2 * cp, g = kp >> 2, jj = kp & 3;
            int off0 = ((c >> 4) * 256) + (g * 64) + ((c & 15) * 4) + jj;
            lds[buf][2][off0]     = bpk[0][it * 2 + 0];
            lds[buf][3][off0]     = bpk[1][it * 2 + 0];
            lds[buf][2][off0 + 4] = bpk[0][it * 2 + 1];   // col c+1 (c even -> stays in-chunk)
            lds[buf][3][off0 + 4] = bpk[1][it * 2 + 1];
        }
    };

    auto ldfrag = [&](const unsigned* p) -> bf16x8 {
        return __builtin_bit_cast(bf16x8, *(const u32x4*)p);
    };

    auto compute = [&](int buf) {
        bf16x8 ah[4], al[4], bh[4], bl[4];
        #pragma unroll
        for (int mt = 0; mt < 4; ++mt) {
            int sub = wr * 4 + mt;
            ah[mt] = ldfrag(&lds[buf][0][sub * 256 + lane * 4]);
            al[mt] = ldfrag(&lds[buf][1][sub * 256 + lane * 4]);
        }
        #pragma unroll
        for (int nt = 0; nt < 4; ++nt) {
            int sub = wc * 4 + nt;
            bh[nt] = ldfrag(&lds[buf][2][sub * 256 + lane * 4]);
            bl[nt] = ldfrag(&lds[buf][3][sub * 256 + lane * 4]);
        }
        #pragma unroll
        for (int mt = 0; mt < 4; ++mt)
            #pragma unroll
            for (int nt = 0; nt < 4; ++nt) {
                acc[mt][nt] = __builtin_amdgcn_mfma_f32_16x16x32_bf16(ah[mt], bh[nt], acc[mt][nt], 0, 0, 0);
                acc[mt][nt] = __builtin_amdgcn_mfma_f32_16x16x32_bf16(ah[mt], bl[nt], acc[mt][nt], 0, 0, 0);
                acc[mt][nt] = __builtin_amdgcn_mfma_f32_16x16x32_bf16(al[mt], bh[nt], acc[mt][nt], 0, 0, 0);
            }
    };

    stage(0);
    commit(0);
    __syncthreads();
    int buf = 0;
    for (int k0 = 32; k0 < Kc; k0 += 32) {
        stage(k0);          // next tile's global loads in flight...
        compute(buf);       // ...while MFMAs consume the current tile
        commit(buf ^ 1);
        __syncthreads();
        buf ^= 1;
    }
    compute(buf);

    const int rb0 = (lane >> 4) * 4, cc = lane & 15;
    #pragma unroll
    for (int mt = 0; mt < 4; ++mt) {
        #pragma unroll
        for (int nt = 0; nt < 4; ++nt) {
            int col = n0 + wc * 64 + nt * 16 + cc;
            int row = m0 + wr * 64 + mt * 16 + rb0;
            float b = bias ? bias[col] : 0.f;
            #pragma unroll
            for (int reg = 0; reg < 4; ++reg) {
                float x = acc[mt][nt][reg] + b;
                if (act) x = 0.5f * x * (1.f + erff(x * 0.70710678118654752f)); // exact gelu
                Cp[(size_t)(row + reg) * N + col] = x;
            }
        }
    }
}

// ---------------------------------------------------------------------------
// indexer: hierarchical product-key top-k.  1 block (64 threads = 1 wave) per
// (b,e) row.  Sets at each level are order-invariant downstream, so iterative
// argmax extraction is sufficient.
// ---------------------------------------------------------------------------
__device__ inline void wave_topk10(volatile float* a, int cnt,
                                   float* vnew, int* inew, int t)
{
    for (int iter = 0; iter < 10; ++iter) {
        float bv = -FLT_MAX;
        int bi = 0x7fffffff;
        for (int n = t; n < cnt; n += 64) {
            float v = a[n];
            if (v > bv) { bv = v; bi = n; }
        }
        #pragma unroll
        for (int off = 32; off; off >>= 1) {
            float ov = __shfl_xor(bv, off, 64);
            int   oi = __shfl_xor(bi, off, 64);
            if (ov > bv || (ov == bv && oi < bi)) { bv = ov; bi = oi; }
        }
        if (t == 0) { vnew[iter] = bv; inew[iter] = bi; a[bi] = -FLT_MAX; }
        __syncthreads();
    }
}

__global__ __launch_bounds__(64) void indexer_kernel(
    const float* __restrict__ qidx,   // [BE][256]
    const float* __restrict__ key0,   // [100][64]
    const float* __restrict__ key1,   // [100][10][64]
    const float* __restrict__ key2,   // [1000][10][64]
    const float* __restrict__ key3,   // [10000][5][64]
    float* __restrict__ e2n_val,      // [BE][10]
    int* __restrict__ e2n_ind)        // [BE][10]
{
    const int be = blockIdx.x;
    const int t = threadIdx.x;
    __shared__ float q[256];
    __shared__ float sraw[100];
    __shared__ float a[100];
    __shared__ float vnew[10]; __shared__ int inew[10];
    __shared__ float vcur[10]; __shared__ int icur[10];
    __shared__ float km[10], ks[10];

    for (int idx = t; idx < 256; idx += 64) q[idx] = qidx[(size_t)be * 256 + idx];
    __syncthreads();

    // ---- level 0: softmax over 100 nodes, top-10 ----
    for (int n = t; n < 100; n += 64) {
        float dot = 0.f;
        const float* kp = key0 + (size_t)n * 64;
        #pragma unroll 8
        for (int d = 0; d < 64; ++d) dot += q[d] * kp[d];
        sraw[n] = dot * 0.125f;   // / sqrt(64)
    }
    __syncthreads();
    float lm = -FLT_MAX;
    for (int n = t; n < 100; n += 64) lm = fmaxf(lm, sraw[n]);
    #pragma unroll
    for (int off = 32; off; off >>= 1) lm = fmaxf(lm, __shfl_xor(lm, off, 64));
    float lsum = 0.f;
    for (int n = t; n < 100; n += 64) { float e = expf(sraw[n] - lm); a[n] = e; lsum += e; }
    #pragma unroll
    for (int off = 32; off; off >>= 1) lsum += __shfl_xor(lsum, off, 64);
    __syncthreads();
    for (int n = t; n < 100; n += 64) a[n] /= lsum;
    __syncthreads();
    wave_topk10(a, 100, vnew, inew, t);
    if (t == 0) {
        float s = 0.f;
        for (int u = 0; u < 10; ++u) s += vnew[u];
        for (int u = 0; u < 10; ++u) { vcur[u] = vnew[u] / s; icur[u] = inew[u]; }
    }
    __syncthreads();

    // ---- levels 1..3 ----
    for (int lvl = 1; lvl < 4; ++lvl) {
        const int br = (lvl < 3) ? 10 : 5;
        const float* kb = (lvl == 1) ? key1 : ((lvl == 2) ? key2 : key3);
        const int cnt = 10 * br;
        const float* qv = q + lvl * 64;
        for (int c = t; c < cnt; c += 64) {
            int k = c / br, cc = c - k * br;
            const float* kp = kb + ((size_t)icur[k] * br + cc) * 64;
            float dot = 0.f;
            #pragma unroll 8
            for (int d = 0; d < 64; ++d) dot += qv[d] * kp[d];
            sraw[c] = dot * 0.125f;
        }
        __syncthreads();
        if (t < 10) {  // per-k softmax over branch
            float m = -FLT_MAX;
            for (int cc = 0; cc < br; ++cc) m = fmaxf(m, sraw[t * br + cc]);
            float s = 0.f;
            for (int cc = 0; cc < br; ++cc) s += expf(sraw[t * br + cc] - m);
            km[t] = m; ks[t] = s;
        }
        __syncthreads();
        for (int c = t; c < cnt; c += 64) {
            int k = c / br;
            a[c] = vcur[k] * expf(sraw[c] - km[k]) / ks[k];
        }
        __syncthreads();
        wave_topk10(a, cnt, vnew, inew, t);
        if (t == 0) {
            float s = 0.f;
            for (int u = 0; u < 10; ++u) s += vnew[u];
            int ni[10]; float nv[10];
            for (int u = 0; u < 10; ++u) {
                int f = inew[u];
                ni[u] = icur[f / br] * br + (f % br);
                nv[u] = vnew[u] / s;
            }
            for (int u = 0; u < 10; ++u) { icur[u] = ni[u]; vcur[u] = nv[u]; }
        }
        __syncthreads();
    }
    if (t < 10) {
        e2n_val[(size_t)be * 10 + t] = vcur[t];
        e2n_ind[(size_t)be * 10 + t] = icur[t];
    }
}

// ---------------------------------------------------------------------------
// per (r, b, i): build LDS hash of the 1000 scattered candidates (coalesced
// e22n row), compute e222e row -> loss, then top-100 columns by RADIX SELECT
// over float bits (positive floats are uint-monotonic; top-100 is guaranteed
// all-positive since each row has >=~500 positive nnz). Output is the SET of
// top-100 columns — order irrelevant (softmax over slots is perm-invariant).
// ---------------------------------------------------------------------------
__global__ __launch_bounds__(256) void scatter_loss_topk_kernel(
    const int* __restrict__ e2n_ind,   // [B][E][10]
    const float* __restrict__ e2n_val, // [B][E][10]
    const int* __restrict__ edges,     // [R][N][WK]
    const float* __restrict__ wts,     // [R][N][WK]
    const float* __restrict__ e2e,     // [B][R][E][E]
    int* __restrict__ top_ind,         // [BE][R][100]
    float* __restrict__ loss_acc)
{
    __shared__ int   hkey[HASH_SZ];
    __shared__ float hval[HASH_SZ];
    // pool phases: (1) s_ind[1280]+s_val[1280]  (2) hist[2048]  (3) bcol[1024]+bval[1024]
    __shared__ int   pool[2560];
    __shared__ float red[256];
    __shared__ int   chunkSuf[256];
    __shared__ int   s_t, s_above, s_cntA, s_cntB;

    const int blk = blockIdx.x;
    const int r = blk >> 9;        // blk / 512
    const int be = blk & 511;
    const int b = be >> 7, i = be & 127;
    const int tid = threadIdx.x;

    int* s_ind = pool;
    float* s_val = (float*)(pool + 1280);

    for (int idx = tid; idx < E_SZ * KTOP; idx += 256) {
        s_ind[idx] = e2n_ind[(size_t)b * E_SZ * KTOP + idx];
        s_val[idx] = e2n_val[(size_t)b * E_SZ * KTOP + idx];
    }
    for (int idx = tid; idx < HASH_SZ; idx += 256) { hkey[idx] = -1; hval[idx] = 0.f; }
    if (tid == 0) { s_t = -1; s_above = 0; s_cntA = 0; s_cntB = 0; }
    __syncthreads();

    // scatter-add 1000 candidates into the hash
    const size_t rbase = (size_t)r * N_NODES * WK;
    for (int c = tid; c < KTOP * WK; c += 256) {
        int k = c / WK, wk = c - k * WK;
        int node = s_ind[i * KTOP + k];
        float v0 = s_val[i * KTOP + k];
        size_t off = rbase + (size_t)node * WK + wk;
        int col = edges[off];
        float v = v0 * wts[off];
        unsigned h = ((unsigned)col * 2654435761u) >> 21;  // top 11 bits
        for (;;) {
            int old = atomicCAS(&hkey[h], -1, col);
            if (old == -1 || old == col) { atomicAdd(&hval[h], v); break; }
            h = (h + 1) & HASH_MASK;
        }
    }
    __syncthreads();

    // e222e row i of batch b (vs all j): 256 threads = 128 j x 2 k-halves
    {
        const int j = tid & 127, half = tid >> 7;
        float acc = 0.f;
        #pragma unroll
        for (int k = half * 5; k < half * 5 + 5; ++k) {
            int col = s_ind[j * KTOP + k];
            float vv = s_val[j * KTOP + k];
            unsigned h = ((unsigned)col * 2654435761u) >> 21;
            float g = 0.f;
            for (;;) {
                int kk = hkey[h];
                if (kk == col) { g = hval[h]; break; }
                if (kk == -1) break;
                h = (h + 1) & HASH_MASK;
            }
            acc += vv * g;
        }
        red[tid] = acc;
        __syncthreads();
        float sq = 0.f;
        if (tid < 128) {
            float tot = red[tid] + red[tid + 128];
            float d = tot - e2e[(((size_t)b * R_HEADS + r) * E_SZ + i) * E_SZ + tid];
            sq = d * d;
        }
        __syncthreads();
        red[tid] = sq;
        __syncthreads();
        for (int off = 128; off; off >>= 1) {
            if (tid < off) red[tid] += red[tid + off];
            __syncthreads();
        }
        if (tid == 0) atomicAdd(loss_acc, red[0]);
    }
    __syncthreads();   // also: s_ind/s_val dead from here -> pool reusable

    // ---- radix select: histogram on float bits [30:20] (2048 bins) ----
    int* hist = pool;
    for (int idx = tid; idx < HASH_SZ; idx += 256) hist[idx] = 0;
    __syncthreads();
    for (int idx = tid; idx < HASH_SZ; idx += 256) {
        float v = hval[idx];
        if (hkey[idx] != -1 && v > 0.f)
            atomicAdd(&hist[(__float_as_uint(v) >> 20) & 0x7FF], 1);
    }
    __syncthreads();
    {
        int csum = 0;
        #pragma unroll
        for (int bb = 0; bb < 8; ++bb) csum += hist[tid * 8 + bb];
        chunkSuf[tid] = csum;
    }
    __syncthreads();
    if (tid == 0) {   // suffix over 256 chunk sums (count in chunks ABOVE c)
        int suf = 0;
        for (int c = 255; c >= 0; --c) { int t0 = chunkSuf[c]; chunkSuf[c] = suf; suf += t0; }
    }
    __syncthreads();
    {   // find threshold bin t: count(bins > t) < 100 <= count(bins >= t)
        int cum = chunkSuf[tid];
        for (int bb = tid * 8 + 7; bb >= tid * 8; --bb) {
            int h = hist[bb];
            if (cum < READ_K && cum + h >= READ_K) { s_t = bb; s_above = cum; }
            cum += h;
        }
    }
    __syncthreads();
    const int tbin = s_t;   // -1 only if <100 positive values (guaranteed not; safe anyway)

    // ---- compaction pass: emit above-threshold cols, stash boundary bin ----
    int* bcol = pool;                 // reuses hist (dead after sync below)
    float* bval = (float*)(pool + 1024);
    __syncthreads();
    int* outp = top_ind + ((size_t)be * R_HEADS + r) * READ_K;
    for (int idx = tid; idx < HASH_SZ; idx += 256) {
        float v = hval[idx];
        if (hkey[idx] == -1 || v <= 0.f) continue;
        int bin = (__float_as_uint(v) >> 20) & 0x7FF;
        if (bin > tbin) {
            int p = atomicAdd(&s_cntA, 1);
            if (p < READ_K) outp[p] = hkey[idx];
        } else if (bin == tbin) {
            int p = atomicAdd(&s_cntB, 1);
            bcol[p] = hkey[idx]; bval[p] = v;
        }
    }
    __syncthreads();
    const int above = s_cntA;
    const int m = s_cntB;
    int rem = READ_K - above;
    if (rem >= m) {
        // take the whole boundary bin (rem==m when tbin valid); pad if short
        for (int idx = tid; idx < m; idx += 256) outp[above + idx] = bcol[idx];
        for (int idx = above + m + tid; idx < READ_K; idx += 256) outp[idx] = 0;
    } else if (tid < 64) {
        // wave-iterative argmax for the boundary remainder (m typically ~8-30)
        volatile float* bv_ = bval;
        for (int it = 0; it < rem; ++it) {
            float bvx = -FLT_MAX; int bi = -1;
            for (int n = tid; n < m; n += 64) {
                float v = bv_[n];
                if (v > bvx) { bvx = v; bi = n; }
            }
            #pragma unroll
            for (int off = 32; off; off >>= 1) {
                float ov = __shfl_xor(bvx, off, 64);
                int   oi = __shfl_xor(bi, off, 64);
                if (ov > bvx) { bvx = ov; bi = oi; }
            }
            if (tid == 0) { outp[above + it] = bcol[bi]; bv_[bi] = -FLT_MAX; }
        }
    }
}

// ---------------------------------------------------------------------------
// attention read: per (r,b,e) gather 110 value rows to LDS (stride 65 to
// avoid the stride-64 bank conflict), score vs qh, softmax, weighted sum.
// ---------------------------------------------------------------------------
__global__ __launch_bounds__(128) void attn_kernel(
    const float* __restrict__ qh,      // [BE][768]
    const int* __restrict__ e2n_ind,   // [BE][10]
    const int* __restrict__ top_ind,   // [BE][R][100]
    const float* __restrict__ memv,    // [R][N][64]
    float* __restrict__ attd)          // [BE][768]
{
    __shared__ float vv[SLOTS * 65];
    __shared__ int slots[SLOTS];
    __shared__ float qv[64];
    __shared__ float sc[SLOTS];
    __shared__ float red[128];

    const int blk = blockIdx.x;
    const int r = blk >> 9, be = blk & 511;
    const int tid = threadIdx.x;

    if (tid < KTOP) slots[tid] = e2n_ind[(size_t)be * KTOP + tid];
    else if (tid < SLOTS) slots[tid] = top_ind[((size_t)be * R_HEADS + r) * READ_K + (tid - KTOP)];
    if (tid < 64) qv[tid] = qh[(size_t)be * H_DIM + r * 64 + tid];
    __syncthreads();

    const size_t rb = (size_t)r * N_NODES * 64;
    for (int idx = tid; idx < SLOTS * 64; idx += 128) {
        int s = idx >> 6, d = idx & 63;
        vv[s * 65 + d] = memv[rb + (size_t)slots[s] * 64 + d];
    }
    __syncthreads();

    if (tid < SLOTS) {
        float dot = 0.f;
        const float* vp = vv + tid * 65;
        #pragma unroll 8
        for (int d = 0; d < 64; ++d) dot += qv[d] * vp[d];
        sc[tid] = dot * 0.125f;   // / sqrt(64)
    }
    __syncthreads();

    red[tid] = (tid < SLOTS) ? sc[tid] : -FLT_MAX;
    __syncthreads();
    for (int off = 64; off; off >>= 1) {
        if (tid < off) red[tid] = fmaxf(red[tid], red[tid + off]);
        __syncthreads();
    }
    float m = red[0];
    __syncthreads();
    float e = (tid < SLOTS) ? expf(sc[tid] - m) : 0.f;
    red[tid] = e;
    __syncthreads();
    for (int off = 64; off; off >>= 1) {
        if (tid < off) red[tid] += red[tid + off];
        __syncthreads();
    }
    float sum = red[0];
    if (tid < SLOTS) sc[tid] = e / sum;
    __syncthreads();

    // weighted sum: wave 0 sums slots 0..54, wave 1 sums 55..109, combine.
    {
        const int d = tid & 63;
        const int s0 = (tid >> 6) * 55;
        float acc = 0.f;
        for (int s = s0; s < s0 + 55; ++s) acc += sc[s] * vv[s * 65 + d];
        red[tid] = acc;
        __syncthreads();
        if (tid < 64)
            attd[(size_t)be * H_DIM + r * 64 + tid] = red[tid] + red[tid + 64];
    }
}

// ---------------------------------------------------------------------------
// layernorm over H=768 per row; input is 4 split-K partials of h2 plus b2.
// ---------------------------------------------------------------------------
__global__ __launch_bounds__(256) void ln_kernel(
    const float* __restrict__ hp,   // [4][BE][768] split-K partials
    const float* __restrict__ b2,   // [768]
    const float* __restrict__ g,
    const float* __restrict__ bta, float* __restrict__ out)
{
    const int be = blockIdx.x, tid = threadIdx.x;
    __shared__ float red[256];
    const size_t st = (size_t)BE * H_DIM;
    const size_t base = (size_t)be * 768;
    float x0 = b2[tid], x1 = b2[tid + 256], x2 = b2[tid + 512];
    #pragma unroll
    for (int s = 0; s < 4; ++s) {
        x0 += hp[s * st + base + tid];
        x1 += hp[s * st + base + 256 + tid];
        x2 += hp[s * st + base + 512 + tid];
    }
    red[tid] = x0 + x1 + x2;
    __syncthreads();
    for (int off = 128; off; off >>= 1) { if (tid < off) red[tid] += red[tid + off]; __syncthreads(); }
    const float mu = red[0] * (1.f / 768.f);
    __syncthreads();
    const float d0 = x0 - mu, d1 = x1 - mu, d2 = x2 - mu;
    red[tid] = d0 * d0 + d1 * d1 + d2 * d2;
    __syncthreads();
    for (int off = 128; off; off >>= 1) { if (tid < off) red[tid] += red[tid + off]; __syncthreads(); }
    const float rstd = rsqrtf(red[0] * (1.f / 768.f) + 1e-5f);
    out[(size_t)be * 768 + tid]       = d0 * rstd * g[tid]       + bta[tid];
    out[(size_t)be * 768 + 256 + tid] = d1 * rstd * g[tid + 256] + bta[tid + 256];
    out[(size_t)be * 768 + 512 + tid] = d2 * rstd * g[tid + 512] + bta[tid + 512];
}

// ---------------------------------------------------------------------------
extern "C" void kernel_launch(void* const* d_in, const int* in_sizes, int n_in,
                              void* d_out, int out_size, void* d_ws, size_t ws_size,
                              hipStream_t stream)
{
    const float* elem_hiddens = (const float*)d_in[0];
    const float* e2e          = (const float*)d_in[1];
    const float* Wq_idx       = (const float*)d_in[2];
    const float* bq_idx       = (const float*)d_in[3];
    const float* key0         = (const float*)d_in[4];
    const float* key1         = (const float*)d_in[5];
    const float* key2         = (const float*)d_in[6];
    const float* key3         = (const float*)d_in[7];
    // d_in[8] = memory_keys: UNUSED by the reference output
    const float* memv         = (const float*)d_in[9];
    const float* wir_w        = (const float*)d_in[10];
    const float* Wq_mha       = (const float*)d_in[11];
    const float* bq_mha       = (const float*)d_in[12];
    const float* W1           = (const float*)d_in[13];
    const float* b1           = (const float*)d_in[14];
    const float* W2           = (const float*)d_in[15];
    const float* b2           = (const float*)d_in[16];
    const float* ln_g         = (const float*)d_in[17];
    const float* ln_b         = (const float*)d_in[18];
    const int*   wir_e        = (const int*)d_in[19];
    float* out = (float*)d_out;

    char* ws = (char*)d_ws;
    float* loss    = (float*)ws;                         // 256 B reserved
    float* q_idx   = (float*)(ws + 256);                 // 512*256
    float* qh      = q_idx + (size_t)BE * 256;           // 512*768
    float* e2n_val = qh + (size_t)BE * H_DIM;            // 512*10
    int*   e2n_ind = (int*)(e2n_val + BE * KTOP);        // 512*10
    int*   top_ind = e2n_ind + BE * KTOP;                // 512*12*100
    float* attd    = (float*)(top_ind + (size_t)BE * R_HEADS * READ_K); // 512*768
    float* h1      = attd + (size_t)BE * H_DIM;          // 512*3072
    float* h2p     = h1 + (size_t)BE * INTER;            // 4*512*768 split-K partials

    zero_loss_kernel<<<1, 64, 0, stream>>>(loss);

    // q_idx projection: exact f32 (feeds discrete top-k selection);
    // dbuf variant with identical per-output FMA order -> bitwise == baseline
    gemm_kernel<<<dim3(256 / 64, BE / 64), 256, 0, stream>>>(
        elem_hiddens, Wq_idx, bq_idx, q_idx, BE, 256, H_DIM, 0);
    // qh projection: split-bf16 MFMA (~1e-5 rel err; feeds continuous attn)
    gemm_mfma_kernel<<<dim3(H_DIM / 128, BE / 128, 1), 256, 0, stream>>>(
        elem_hiddens, Wq_mha, bq_mha, qh, BE, H_DIM, H_DIM, H_DIM, 0);

    // hierarchical indexer
    indexer_kernel<<<BE, 64, 0, stream>>>(q_idx, key0, key1, key2, key3,
                                          e2n_val, e2n_ind);

    // per (r,b,i): hash scatter, write-loss, top-100 via radix select
    scatter_loss_topk_kernel<<<R_HEADS * BE, 256, 0, stream>>>(
        e2n_ind, e2n_val, wir_e, wir_w, e2e, top_ind, loss);

    // attention read over 110 slots per (b,e,r)
    attn_kernel<<<R_HEADS * BE, 128, 0, stream>>>(qh, e2n_ind, top_ind, memv, attd);

    // MLP: h1 = gelu(attd @ W1 + b1), MFMA
    gemm_mfma_kernel<<<dim3(INTER / 128, BE / 128, 1), 256, 0, stream>>>(
        attd, W1, b1, h1, BE, INTER, H_DIM, H_DIM, 1);
    // h2 partials = h1 @ W2, MFMA split-K=4 (chunk 768, lda=3072), no bias
    gemm_mfma_kernel<<<dim3(H_DIM / 128, BE / 128, 4), 256, 0, stream>>>(
        h1, W2, nullptr, h2p, BE, H_DIM, INTER / 4, INTER, 0);

    // layernorm( sum partials + b2 ) -> out[0..393215], loss -> out[393216]
    ln_kernel<<<BE, 256, 0, stream>>>(h2p, b2, ln_g, ln_b, out);
    write_loss_kernel<<<1, 64, 0, stream>>>(loss, out + (size_t)BE * H_DIM);
}

// Round 5
// 1015.379 us; speedup vs baseline: 1.0387x; 1.0387x over previous
//
#include <hip/hip_runtime.h>
#include <hip/hip_bf16.h>
#include <cfloat>
#include <cmath>

// Problem constants
#define H_DIM 768
#define IDX_D 64
#define KTOP 10
#define R_HEADS 12
#define READ_K 100
#define MD 64
#define WK 100
#define INTER 3072
#define N_NODES 50000
#define B_SZ 4
#define E_SZ 128
#define BE 512            // B*E
#define SLOTS 110         // KTOP + READ_K
#define HASH_SZ 2048
#define HASH_MASK 2047

// ---------------------------------------------------------------------------
// small utility kernels
// ---------------------------------------------------------------------------
__global__ void zero_loss_kernel(float* p) {
    if (threadIdx.x == 0 && blockIdx.x == 0) *p = 0.f;
}
__global__ void write_loss_kernel(const float* p, float* out) {
    if (threadIdx.x == 0 && blockIdx.x == 0) out[0] = *p / 65536.f;  // / (B*E*E)
}

// ---------------------------------------------------------------------------
// f32 GEMM, register-prefetch double-buffered LDS. Per-output FMA order is
// k-ascending with the same micro-tile as the harness-verified baseline ->
// bitwise-identical results (used for q_idx, which feeds discrete top-k).
// ---------------------------------------------------------------------------
__global__ __launch_bounds__(256) void gemm_kernel(
    const float* __restrict__ A, const float* __restrict__ Bm,
    const float* __restrict__ bias, float* __restrict__ C,
    int M, int N, int K, int act)
{
    __shared__ float As[2][16][65];
    __shared__ float Bs[2][16][65];
    const int tid = threadIdx.x;
    const int tx = tid & 15, ty = tid >> 4;
    const int m0 = blockIdx.y * 64, n0 = blockIdx.x * 64;

    const int aty = tid >> 4, atx = tid & 15;   // A staging: rows aty+16j, col atx
    const int bky = tid >> 6, bnx = tid & 63;   // B staging: rows bky+4j, col bnx

    float acc[4][4] = {};
    float av[4], bv[4];

    auto stage = [&](int k0) {
        #pragma unroll
        for (int j = 0; j < 4; ++j)
            av[j] = A[(size_t)(m0 + aty + 16 * j) * K + k0 + atx];
        #pragma unroll
        for (int j = 0; j < 4; ++j)
            bv[j] = Bm[(size_t)(k0 + bky + 4 * j) * N + n0 + bnx];
    };
    auto commit = [&](int buf) {
        #pragma unroll
        for (int j = 0; j < 4; ++j) As[buf][atx][aty + 16 * j] = av[j];
        #pragma unroll
        for (int j = 0; j < 4; ++j) Bs[buf][bky + 4 * j][bnx] = bv[j];
    };
    auto compute = [&](int buf) {
        #pragma unroll
        for (int kk = 0; kk < 16; ++kk) {
            float a4[4], b4[4];
            #pragma unroll
            for (int u = 0; u < 4; ++u) a4[u] = As[buf][kk][ty * 4 + u];
            #pragma unroll
            for (int v = 0; v < 4; ++v) b4[v] = Bs[buf][kk][tx * 4 + v];
            #pragma unroll
            for (int u = 0; u < 4; ++u)
                #pragma unroll
                for (int v = 0; v < 4; ++v) acc[u][v] += a4[u] * b4[v];
        }
    };

    stage(0);
    commit(0);
    __syncthreads();
    int buf = 0;
    for (int k0 = 16; k0 < K; k0 += 16) {
        stage(k0);
        compute(buf);
        commit(buf ^ 1);
        __syncthreads();
        buf ^= 1;
    }
    compute(buf);

    #pragma unroll
    for (int u = 0; u < 4; ++u) {
        int m = m0 + ty * 4 + u;
        #pragma unroll
        for (int v = 0; v < 4; ++v) {
            int n = n0 + tx * 4 + v;
            float x = acc[u][v] + bias[n];
            if (act) x = 0.5f * x * (1.f + erff(x * 0.70710678118654752f));
            C[(size_t)m * N + n] = x;
        }
    }
}

// ---------------------------------------------------------------------------
// split-bf16 MFMA GEMM (verified this session: absmax 1.95e-3 overall pass).
// C ~= Ahi*Bhi + Ahi*Blo + Alo*Bhi; 128x128 tile, 4 waves, 16x16x32 bf16.
// ---------------------------------------------------------------------------
typedef short bf16x8 __attribute__((ext_vector_type(8)));   // 8 bf16 in 4 VGPRs
typedef float f32x4 __attribute__((ext_vector_type(4)));
typedef unsigned int u32x4 __attribute__((ext_vector_type(4)));

__device__ inline unsigned f2bf(float x) {          // f32 -> bf16 bits (RNE)
    unsigned u = __float_as_uint(x);
    return (u + 0x7FFFu + ((u >> 16) & 1u)) >> 16;
}
__device__ inline float bfval(unsigned b) { return __uint_as_float(b << 16); }

__global__ __launch_bounds__(256) void gemm_mfma_kernel(
    const float* __restrict__ A, const float* __restrict__ Bm,
    const float* __restrict__ bias, float* __restrict__ C,
    int M, int N, int Kc, int lda, int act)
{
    __shared__ __align__(16) unsigned int lds[2][4][2048];

    const int tid = threadIdx.x;
    const int lane = tid & 63;
    const int w = tid >> 6, wr = w >> 1, wc = w & 1;
    const int m0 = blockIdx.y * 128, n0 = blockIdx.x * 128;
    const int kbase = blockIdx.z * Kc;
    float* __restrict__ Cp = C + (size_t)blockIdx.z * M * N;

    f32x4 acc[4][4] = {};
    unsigned apk[2][8];
    unsigned bpk[2][8];

    auto stage = [&](int k0) {
        #pragma unroll
        for (int it = 0; it < 8; ++it) {
            int idx = it * 256 + tid;
            int r = idx >> 4, p = idx & 15;
            const float2 v = *(const float2*)(A + (size_t)(m0 + r) * lda + kbase + k0 + 2 * p);
            unsigned h0 = f2bf(v.x), h1 = f2bf(v.y);
            apk[0][it] = h0 | (h1 << 16);
            apk[1][it] = f2bf(v.x - bfval(h0)) | (f2bf(v.y - bfval(h1)) << 16);
        }
        #pragma unroll
        for (int it = 0; it < 4; ++it) {
            int idx = it * 256 + tid;
            int cp = idx & 63, kp = idx >> 6;
            const float* bp = Bm + (size_t)(kbase + k0 + 2 * kp) * N + n0 + 2 * cp;
            const float2 e = *(const float2*)bp;
            const float2 o = *(const float2*)(bp + N);
            unsigned he0 = f2bf(e.x), ho0 = f2bf(o.x);
            unsigned he1 = f2bf(e.y), ho1 = f2bf(o.y);
            bpk[0][it * 2 + 0] = he0 | (ho0 << 16);
            bpk[1][it * 2 + 0] = f2bf(e.x - bfval(he0)) | (f2bf(o.x - bfval(ho0)) << 16);
            bpk[0][it * 2 + 1] = he1 | (ho1 << 16);
            bpk[1][it * 2 + 1] = f2bf(e.y - bfval(he1)) | (f2bf(o.y - bfval(ho1)) << 16);
        }
    };

    auto commit = [&](int buf) {
        #pragma unroll
        for (int it = 0; it < 8; ++it) {
            int idx = it * 256 + tid;
            int r = idx >> 4, p = idx & 15;
            int off = ((r >> 4) * 256) + ((p >> 2) * 64) + ((r & 15) * 4) + (p & 3);
            lds[buf][0][off] = apk[0][it];
            lds[buf][1][off] = apk[1][it];
        }
        #pragma unroll
        for (int it = 0; it < 4; ++it) {
            int idx = it * 256 + tid;
            int cp = idx & 63, kp = idx >> 6;
            int c = 2 * cp, g = kp >> 2, jj = kp & 3;
            int off0 = ((c >> 4) * 256) + (g * 64) + ((c & 15) * 4) + jj;
            lds[buf][2][off0]     = bpk[0][it * 2 + 0];
            lds[buf][3][off0]     = bpk[1][it * 2 + 0];
            lds[buf][2][off0 + 4] = bpk[0][it * 2 + 1];
            lds[buf][3][off0 + 4] = bpk[1][it * 2 + 1];
        }
    };

    auto ldfrag = [&](const unsigned* p) -> bf16x8 {
        return __builtin_bit_cast(bf16x8, *(const u32x4*)p);
    };

    auto compute = [&](int buf) {
        bf16x8 ah[4], al[4], bh[4], bl[4];
        #pragma unroll
        for (int mt = 0; mt < 4; ++mt) {
            int sub = wr * 4 + mt;
            ah[mt] = ldfrag(&lds[buf][0][sub * 256 + lane * 4]);
            al[mt] = ldfrag(&lds[buf][1][sub * 256 + lane * 4]);
        }
        #pragma unroll
        for (int nt = 0; nt < 4; ++nt) {
            int sub = wc * 4 + nt;
            bh[nt] = ldfrag(&lds[buf][2][sub * 256 + lane * 4]);
            bl[nt] = ldfrag(&lds[buf][3][sub * 256 + lane * 4]);
        }
        #pragma unroll
        for (int mt = 0; mt < 4; ++mt)
            #pragma unroll
            for (int nt = 0; nt < 4; ++nt) {
                acc[mt][nt] = __builtin_amdgcn_mfma_f32_16x16x32_bf16(ah[mt], bh[nt], acc[mt][nt], 0, 0, 0);
                acc[mt][nt] = __builtin_amdgcn_mfma_f32_16x16x32_bf16(ah[mt], bl[nt], acc[mt][nt], 0, 0, 0);
                acc[mt][nt] = __builtin_amdgcn_mfma_f32_16x16x32_bf16(al[mt], bh[nt], acc[mt][nt], 0, 0, 0);
            }
    };

    stage(0);
    commit(0);
    __syncthreads();
    int buf = 0;
    for (int k0 = 32; k0 < Kc; k0 += 32) {
        stage(k0);
        compute(buf);
        commit(buf ^ 1);
        __syncthreads();
        buf ^= 1;
    }
    compute(buf);

    const int rb0 = (lane >> 4) * 4, cc = lane & 15;
    #pragma unroll
    for (int mt = 0; mt < 4; ++mt) {
        #pragma unroll
        for (int nt = 0; nt < 4; ++nt) {
            int col = n0 + wc * 64 + nt * 16 + cc;
            int row = m0 + wr * 64 + mt * 16 + rb0;
            float b = bias ? bias[col] : 0.f;
            #pragma unroll
            for (int reg = 0; reg < 4; ++reg) {
                float x = acc[mt][nt][reg] + b;
                if (act) x = 0.5f * x * (1.f + erff(x * 0.70710678118654752f));
                Cp[(size_t)(row + reg) * N + col] = x;
            }
        }
    }
}

// ---------------------------------------------------------------------------
// indexer: hierarchical product-key top-k. 1 wave per (b,e) row.
// float4 LOADS with strictly-sequential accumulation -> bitwise-identical
// dot products to the verified scalar version (no top-k flip risk).
// ---------------------------------------------------------------------------
__device__ inline void wave_topk10(volatile float* a, int cnt,
                                   float* vnew, int* inew, int t)
{
    for (int iter = 0; iter < 10; ++iter) {
        float bv = -FLT_MAX;
        int bi = 0x7fffffff;
        for (int n = t; n < cnt; n += 64) {
            float v = a[n];
            if (v > bv) { bv = v; bi = n; }
        }
        #pragma unroll
        for (int off = 32; off; off >>= 1) {
            float ov = __shfl_xor(bv, off, 64);
            int   oi = __shfl_xor(bi, off, 64);
            if (ov > bv || (ov == bv && oi < bi)) { bv = ov; bi = oi; }
        }
        if (t == 0) { vnew[iter] = bv; inew[iter] = bi; a[bi] = -FLT_MAX; }
        __syncthreads();
    }
}

__device__ inline float dot64_seq(const float* __restrict__ qv,
                                  const float* __restrict__ kp)
{
    // 16 x float4 loads; adds in strictly ascending-d order (bitwise == scalar)
    const float4* k4 = (const float4*)kp;
    const float4* q4 = (const float4*)qv;
    float dot = 0.f;
    #pragma unroll
    for (int d4 = 0; d4 < 16; ++d4) {
        float4 kv = k4[d4];
        float4 qq = q4[d4];
        dot += qq.x * kv.x;
        dot += qq.y * kv.y;
        dot += qq.z * kv.z;
        dot += qq.w * kv.w;
    }
    return dot;
}

__global__ __launch_bounds__(64) void indexer_kernel(
    const float* __restrict__ qidx,   // [BE][256]
    const float* __restrict__ key0,   // [100][64]
    const float* __restrict__ key1,   // [100][10][64]
    const float* __restrict__ key2,   // [1000][10][64]
    const float* __restrict__ key3,   // [10000][5][64]
    float* __restrict__ e2n_val,      // [BE][10]
    int* __restrict__ e2n_ind)        // [BE][10]
{
    const int be = blockIdx.x;
    const int t = threadIdx.x;
    __shared__ __align__(16) float q[256];
    __shared__ float sraw[100];
    __shared__ float a[100];
    __shared__ float vnew[10]; __shared__ int inew[10];
    __shared__ float vcur[10]; __shared__ int icur[10];
    __shared__ float km[10], ks[10];

    for (int idx = t; idx < 256; idx += 64) q[idx] = qidx[(size_t)be * 256 + idx];
    __syncthreads();

    // ---- level 0: softmax over 100 nodes, top-10 ----
    for (int n = t; n < 100; n += 64) {
        sraw[n] = dot64_seq(q, key0 + (size_t)n * 64) * 0.125f;   // / sqrt(64)
    }
    __syncthreads();
    float lm = -FLT_MAX;
    for (int n = t; n < 100; n += 64) lm = fmaxf(lm, sraw[n]);
    #pragma unroll
    for (int off = 32; off; off >>= 1) lm = fmaxf(lm, __shfl_xor(lm, off, 64));
    float lsum = 0.f;
    for (int n = t; n < 100; n += 64) { float e = expf(sraw[n] - lm); a[n] = e; lsum += e; }
    #pragma unroll
    for (int off = 32; off; off >>= 1) lsum += __shfl_xor(lsum, off, 64);
    __syncthreads();
    for (int n = t; n < 100; n += 64) a[n] /= lsum;
    __syncthreads();
    wave_topk10(a, 100, vnew, inew, t);
    if (t == 0) {
        float s = 0.f;
        for (int u = 0; u < 10; ++u) s += vnew[u];
        for (int u = 0; u < 10; ++u) { vcur[u] = vnew[u] / s; icur[u] = inew[u]; }
    }
    __syncthreads();

    // ---- levels 1..3 ----
    for (int lvl = 1; lvl < 4; ++lvl) {
        const int br = (lvl < 3) ? 10 : 5;
        const float* kb = (lvl == 1) ? key1 : ((lvl == 2) ? key2 : key3);
        const int cnt = 10 * br;
        const float* qv = q + lvl * 64;
        for (int c = t; c < cnt; c += 64) {
            int k = c / br, cc = c - k * br;
            const float* kp = kb + ((size_t)icur[k] * br + cc) * 64;
            sraw[c] = dot64_seq(qv, kp) * 0.125f;
        }
        __syncthreads();
        if (t < 10) {  // per-k softmax over branch
            float m = -FLT_MAX;
            for (int cc = 0; cc < br; ++cc) m = fmaxf(m, sraw[t * br + cc]);
            float s = 0.f;
            for (int cc = 0; cc < br; ++cc) s += expf(sraw[t * br + cc] - m);
            km[t] = m; ks[t] = s;
        }
        __syncthreads();
        for (int c = t; c < cnt; c += 64) {
            int k = c / br;
            a[c] = vcur[k] * expf(sraw[c] - km[k]) / ks[k];
        }
        __syncthreads();
        wave_topk10(a, cnt, vnew, inew, t);
        if (t == 0) {
            float s = 0.f;
            for (int u = 0; u < 10; ++u) s += vnew[u];
            int ni[10]; float nv[10];
            for (int u = 0; u < 10; ++u) {
                int f = inew[u];
                ni[u] = icur[f / br] * br + (f % br);
                nv[u] = vnew[u] / s;
            }
            for (int u = 0; u < 10; ++u) { icur[u] = ni[u]; vcur[u] = nv[u]; }
        }
        __syncthreads();
    }
    if (t < 10) {
        e2n_val[(size_t)be * 10 + t] = vcur[t];
        e2n_ind[(size_t)be * 10 + t] = icur[t];
    }
}

// ---------------------------------------------------------------------------
// scatter/loss/topk v2: latency-lean restructure.
// - edge/wt gathers issued BEFORE hash-init (HBM latency hides under init)
// - no s_ind/s_val LDS staging (e2n is tiny and L1/L2-hot)
// - wave-shuffle reductions; Hillis-Steele wave suffix scan replaces the
//   serial 256-iter tid0 loop;  ~8 barriers (was ~20);  LDS 25.1 KB (was 28.5)
// ---------------------------------------------------------------------------
__global__ __launch_bounds__(256) void scatter_loss_topk_kernel(
    const int* __restrict__ e2n_ind,   // [B][E][10]
    const float* __restrict__ e2n_val, // [B][E][10]
    const int* __restrict__ edges,     // [R][N][WK]
    const float* __restrict__ wts,     // [R][N][WK]
    const float* __restrict__ e2e,     // [B][R][E][E]
    int* __restrict__ top_ind,         // [BE][R][100]
    float* __restrict__ loss_acc)
{
    __shared__ int   hkey[HASH_SZ];
    __shared__ float hval[HASH_SZ];
    __shared__ int   pool[HASH_SZ];    // hist | bcol[1024]+bval[1024]
    __shared__ float red[128];
    __shared__ float wred[4];
    __shared__ int   sufw[4];
    __shared__ int   s_t, s_cntA, s_cntB;

    const int blk = blockIdx.x;
    const int r = blk >> 9;
    const int be = blk & 511;
    const int b = be >> 7, i = be & 127;
    const int tid = threadIdx.x;
    const int lane = tid & 63, wid = tid >> 6;

    // ---- phase 0: issue candidate gathers early, then init hash ----
    const size_t rbase = (size_t)r * N_NODES * WK;
    const int be10 = be * KTOP;
    int col0, col1, col2, col3 = -2;
    float val0, val1, val2, val3 = 0.f;
    {
        int c = tid, k = c / WK, wk = c - k * WK;
        int node = e2n_ind[be10 + k]; float v0 = e2n_val[be10 + k];
        size_t off = rbase + (size_t)node * WK + wk;
        col0 = edges[off]; val0 = v0 * wts[off];
    }
    {
        int c = tid + 256, k = c / WK, wk = c - k * WK;
        int node = e2n_ind[be10 + k]; float v0 = e2n_val[be10 + k];
        size_t off = rbase + (size_t)node * WK + wk;
        col1 = edges[off]; val1 = v0 * wts[off];
    }
    {
        int c = tid + 512, k = c / WK, wk = c - k * WK;
        int node = e2n_ind[be10 + k]; float v0 = e2n_val[be10 + k];
        size_t off = rbase + (size_t)node * WK + wk;
        col2 = edges[off]; val2 = v0 * wts[off];
    }
    const bool has3 = (tid + 768) < KTOP * WK;
    if (has3) {
        int c = tid + 768, k = c / WK, wk = c - k * WK;
        int node = e2n_ind[be10 + k]; float v0 = e2n_val[be10 + k];
        size_t off = rbase + (size_t)node * WK + wk;
        col3 = edges[off]; val3 = v0 * wts[off];
    }
    for (int idx = tid; idx < HASH_SZ; idx += 256) { hkey[idx] = -1; hval[idx] = 0.f; }
    if (tid == 0) { s_t = -1; s_cntA = 0; s_cntB = 0; }
    __syncthreads();

    // ---- phase 1: scatter-add into hash ----
    auto insert = [&](int col, float v) {
        unsigned h = ((unsigned)col * 2654435761u) >> 21;
        for (;;) {
            int old = atomicCAS(&hkey[h], -1, col);
            if (old == -1 || old == col) { atomicAdd(&hval[h], v); break; }
            h = (h + 1) & HASH_MASK;
        }
    };
    insert(col0, val0);
    insert(col1, val1);
    insert(col2, val2);
    if (has3) insert(col3, val3);
    __syncthreads();

    // ---- phase 2: e222e row -> loss (wave shuffles, 2 barriers) ----
    {
        const int j = tid & 127, half = tid >> 7;
        const int jb = (b * E_SZ + j) * KTOP;
        float acc = 0.f;
        #pragma unroll
        for (int k = half * 5; k < half * 5 + 5; ++k) {
            int col = e2n_ind[jb + k];
            float vv = e2n_val[jb + k];
            unsigned h = ((unsigned)col * 2654435761u) >> 21;
            float g = 0.f;
            for (;;) {
                int kk = hkey[h];
                if (kk == col) { g = hval[h]; break; }
                if (kk == -1) break;
                h = (h + 1) & HASH_MASK;
            }
            acc += vv * g;
        }
        if (half == 0) red[j] = acc;
        __syncthreads();
        float sq = 0.f;
        if (half == 1) {
            float tot = red[j] + acc;
            float d = tot - e2e[(((size_t)b * R_HEADS + r) * E_SZ + i) * E_SZ + j];
            sq = d * d;
        }
        #pragma unroll
        for (int off = 32; off; off >>= 1) sq += __shfl_xor(sq, off, 64);
        if (lane == 0) wred[wid] = sq;
        __syncthreads();
        if (tid == 0) atomicAdd(loss_acc, wred[0] + wred[1] + wred[2] + wred[3]);
    }

    // ---- phase 3: histogram on float bits [30:20] ----
    int* hist = pool;
    for (int idx = tid; idx < HASH_SZ; idx += 256) hist[idx] = 0;
    __syncthreads();
    for (int idx = tid; idx < HASH_SZ; idx += 256) {
        float v = hval[idx];
        if (hkey[idx] != -1 && v > 0.f)
            atomicAdd(&hist[(__float_as_uint(v) >> 20) & 0x7FF], 1);
    }
    __syncthreads();

    // ---- phase 4: wave suffix-scan over 256 chunk sums + threshold bin ----
    {
        int csum = 0;
        #pragma unroll
        for (int bb = 0; bb < 8; ++bb) csum += hist[tid * 8 + bb];
        int cincl = csum;   // inclusive suffix within wave (Hillis-Steele)
        #pragma unroll
        for (int st = 1; st < 64; st <<= 1) {
            int o = __shfl_down(cincl, st, 64);
            if (lane + st < 64) cincl += o;
        }
        if (lane == 0) sufw[wid] = cincl;
        __syncthreads();
        int aboveW = 0;
        for (int ww = wid + 1; ww < 4; ++ww) aboveW += sufw[ww];
        int cum = aboveW + (cincl - csum);   // count in chunks strictly above mine
        for (int bb = tid * 8 + 7; bb >= tid * 8; --bb) {
            int h = hist[bb];
            if (cum < READ_K && cum + h >= READ_K) s_t = bb;   // unique writer
            cum += h;
        }
    }
    __syncthreads();
    const int tbin = s_t;

    // ---- phase 5: compaction (hist dead -> pool reused as bcol/bval) ----
    int* bcol = pool;
    float* bval = (float*)(pool + 1024);
    int* outp = top_ind + ((size_t)be * R_HEADS + r) * READ_K;
    for (int idx = tid; idx < HASH_SZ; idx += 256) {
        float v = hval[idx];
        if (hkey[idx] == -1 || v <= 0.f) continue;
        int bin = (__float_as_uint(v) >> 20) & 0x7FF;
        if (bin > tbin) {
            int p = atomicAdd(&s_cntA, 1);
            if (p < READ_K) outp[p] = hkey[idx];
        } else if (bin == tbin) {
            int p = atomicAdd(&s_cntB, 1);
            bcol[p] = hkey[idx]; bval[p] = v;
        }
    }
    __syncthreads();
    const int above = s_cntA;
    const int m = s_cntB;
    int rem = READ_K - above;
    if (rem >= m) {
        for (int idx = tid; idx < m; idx += 256) outp[above + idx] = bcol[idx];
        for (int idx = above + m + tid; idx < READ_K; idx += 256) outp[idx] = 0;
    } else if (tid < 64) {
        volatile float* bv_ = bval;
        for (int it = 0; it < rem; ++it) {
            float bvx = -FLT_MAX; int bi = -1;
            for (int n = tid; n < m; n += 64) {
                float v = bv_[n];
                if (v > bvx) { bvx = v; bi = n; }
            }
            #pragma unroll
            for (int off = 32; off; off >>= 1) {
                float ov = __shfl_xor(bvx, off, 64);
                int   oi = __shfl_xor(bi, off, 64);
                if (ov > bvx) { bvx = ov; bi = oi; }
            }
            if (tid == 0) { outp[above + it] = bcol[bi]; bv_[bi] = -FLT_MAX; }
        }
    }
}

// ---------------------------------------------------------------------------
// attention read v2: 256 threads (20 waves/CU vs 10), float4 global gather,
// shuffle-based softmax reductions. LDS [s][65] layout kept (conflict-free
// in both score and weighted-sum phases).
// ---------------------------------------------------------------------------
__global__ __launch_bounds__(256) void attn_kernel(
    const float* __restrict__ qh,      // [BE][768]
    const int* __restrict__ e2n_ind,   // [BE][10]
    const int* __restrict__ top_ind,   // [BE][R][100]
    const float* __restrict__ memv,    // [R][N][64]
    float* __restrict__ attd)          // [BE][768]
{
    __shared__ float vv[SLOTS * 65];
    __shared__ int slots[SLOTS];
    __shared__ float qv[64];
    __shared__ float sc[SLOTS];
    __shared__ float red[256];

    const int blk = blockIdx.x;
    const int r = blk >> 9, be = blk & 511;
    const int tid = threadIdx.x;
    const int lane = tid & 63, wid = tid >> 6;

    if (tid < KTOP) slots[tid] = e2n_ind[(size_t)be * KTOP + tid];
    else if (tid < SLOTS) slots[tid] = top_ind[((size_t)be * R_HEADS + r) * READ_K + (tid - KTOP)];
    if (tid < 64) qv[tid] = qh[(size_t)be * H_DIM + r * 64 + tid];
    __syncthreads();

    // gather: float4 global loads (16B/lane), scalar LDS scatter (2-way max)
    const float4* mv4 = (const float4*)(memv + (size_t)r * N_NODES * 64);
    for (int idx = tid; idx < SLOTS * 16; idx += 256) {
        int s = idx >> 4, q4 = idx & 15;
        float4 v = mv4[(size_t)slots[s] * 16 + q4];
        float* dst = vv + s * 65 + q4 * 4;
        dst[0] = v.x; dst[1] = v.y; dst[2] = v.z; dst[3] = v.w;
    }
    __syncthreads();

    if (tid < SLOTS) {
        float dot = 0.f;
        const float* vp = vv + tid * 65;
        #pragma unroll 8
        for (int d = 0; d < 64; ++d) dot += qv[d] * vp[d];
        sc[tid] = dot * 0.125f;   // / sqrt(64)
    }
    __syncthreads();

    // softmax: wave shuffle reduce + 4-way combine
    float v = (tid < SLOTS) ? sc[tid] : -FLT_MAX;
    #pragma unroll
    for (int off = 32; off; off >>= 1) v = fmaxf(v, __shfl_xor(v, off, 64));
    if (lane == 0) red[wid] = v;
    __syncthreads();
    const float mx = fmaxf(fmaxf(red[0], red[1]), fmaxf(red[2], red[3]));
    float e = (tid < SLOTS) ? expf(sc[tid] - mx) : 0.f;
    float s = e;
    #pragma unroll
    for (int off = 32; off; off >>= 1) s += __shfl_xor(s, off, 64);
    if (lane == 0) red[4 + wid] = s;
    __syncthreads();
    const float sum = red[4] + red[5] + red[6] + red[7];
    if (tid < SLOTS) sc[tid] = e / sum;
    __syncthreads();

    // weighted sum: 4 wave-groups stride the slots, combine
    {
        const int d = tid & 63;
        float acc = 0.f;
        for (int ss = wid; ss < SLOTS; ss += 4) acc += sc[ss] * vv[ss * 65 + d];
        red[tid] = acc;
        __syncthreads();
        if (tid < 64)
            attd[(size_t)be * H_DIM + r * 64 + tid] =
                red[tid] + red[tid + 64] + red[tid + 128] + red[tid + 192];
    }
}

// ---------------------------------------------------------------------------
// layernorm over H=768 per row; input is 4 split-K partials of h2 plus b2.
// ---------------------------------------------------------------------------
__global__ __launch_bounds__(256) void ln_kernel(
    const float* __restrict__ hp,   // [4][BE][768] split-K partials
    const float* __restrict__ b2,   // [768]
    const float* __restrict__ g,
    const float* __restrict__ bta, float* __restrict__ out)
{
    const int be = blockIdx.x, tid = threadIdx.x;
    __shared__ float red[256];
    const size_t st = (size_t)BE * H_DIM;
    const size_t base = (size_t)be * 768;
    float x0 = b2[tid], x1 = b2[tid + 256], x2 = b2[tid + 512];
    #pragma unroll
    for (int s = 0; s < 4; ++s) {
        x0 += hp[s * st + base + tid];
        x1 += hp[s * st + base + 256 + tid];
        x2 += hp[s * st + base + 512 + tid];
    }
    red[tid] = x0 + x1 + x2;
    __syncthreads();
    for (int off = 128; off; off >>= 1) { if (tid < off) red[tid] += red[tid + off]; __syncthreads(); }
    const float mu = red[0] * (1.f / 768.f);
    __syncthreads();
    const float d0 = x0 - mu, d1 = x1 - mu, d2 = x2 - mu;
    red[tid] = d0 * d0 + d1 * d1 + d2 * d2;
    __syncthreads();
    for (int off = 128; off; off >>= 1) { if (tid < off) red[tid] += red[tid + off]; __syncthreads(); }
    const float rstd = rsqrtf(red[0] * (1.f / 768.f) + 1e-5f);
    out[(size_t)be * 768 + tid]       = d0 * rstd * g[tid]       + bta[tid];
    out[(size_t)be * 768 + 256 + tid] = d1 * rstd * g[tid + 256] + bta[tid + 256];
    out[(size_t)be * 768 + 512 + tid] = d2 * rstd * g[tid + 512] + bta[tid + 512];
}

// ---------------------------------------------------------------------------
extern "C" void kernel_launch(void* const* d_in, const int* in_sizes, int n_in,
                              void* d_out, int out_size, void* d_ws, size_t ws_size,
                              hipStream_t stream)
{
    const float* elem_hiddens = (const float*)d_in[0];
    const float* e2e          = (const float*)d_in[1];
    const float* Wq_idx       = (const float*)d_in[2];
    const float* bq_idx       = (const float*)d_in[3];
    const float* key0         = (const float*)d_in[4];
    const float* key1         = (const float*)d_in[5];
    const float* key2         = (const float*)d_in[6];
    const float* key3         = (const float*)d_in[7];
    // d_in[8] = memory_keys: UNUSED by the reference output
    const float* memv         = (const float*)d_in[9];
    const float* wir_w        = (const float*)d_in[10];
    const float* Wq_mha       = (const float*)d_in[11];
    const float* bq_mha       = (const float*)d_in[12];
    const float* W1           = (const float*)d_in[13];
    const float* b1           = (const float*)d_in[14];
    const float* W2           = (const float*)d_in[15];
    const float* b2           = (const float*)d_in[16];
    const float* ln_g         = (const float*)d_in[17];
    const float* ln_b         = (const float*)d_in[18];
    const int*   wir_e        = (const int*)d_in[19];
    float* out = (float*)d_out;

    char* ws = (char*)d_ws;
    float* loss    = (float*)ws;                         // 256 B reserved
    float* q_idx   = (float*)(ws + 256);                 // 512*256
    float* qh      = q_idx + (size_t)BE * 256;           // 512*768
    float* e2n_val = qh + (size_t)BE * H_DIM;            // 512*10
    int*   e2n_ind = (int*)(e2n_val + BE * KTOP);        // 512*10
    int*   top_ind = e2n_ind + BE * KTOP;                // 512*12*100
    float* attd    = (float*)(top_ind + (size_t)BE * R_HEADS * READ_K); // 512*768
    float* h1      = attd + (size_t)BE * H_DIM;          // 512*3072
    float* h2p     = h1 + (size_t)BE * INTER;            // 4*512*768 split-K partials

    zero_loss_kernel<<<1, 64, 0, stream>>>(loss);

    // q_idx projection: exact f32 (feeds discrete top-k selection)
    gemm_kernel<<<dim3(256 / 64, BE / 64), 256, 0, stream>>>(
        elem_hiddens, Wq_idx, bq_idx, q_idx, BE, 256, H_DIM, 0);
    // qh projection: split-bf16 MFMA
    gemm_mfma_kernel<<<dim3(H_DIM / 128, BE / 128, 1), 256, 0, stream>>>(
        elem_hiddens, Wq_mha, bq_mha, qh, BE, H_DIM, H_DIM, H_DIM, 0);

    // hierarchical indexer
    indexer_kernel<<<BE, 64, 0, stream>>>(q_idx, key0, key1, key2, key3,
                                          e2n_val, e2n_ind);

    // per (r,b,i): hash scatter, write-loss, top-100 via radix select
    scatter_loss_topk_kernel<<<R_HEADS * BE, 256, 0, stream>>>(
        e2n_ind, e2n_val, wir_e, wir_w, e2e, top_ind, loss);

    // attention read over 110 slots per (b,e,r)
    attn_kernel<<<R_HEADS * BE, 256, 0, stream>>>(qh, e2n_ind, top_ind, memv, attd);

    // MLP: h1 = gelu(attd @ W1 + b1), MFMA
    gemm_mfma_kernel<<<dim3(INTER / 128, BE / 128, 1), 256, 0, stream>>>(
        attd, W1, b1, h1, BE, INTER, H_DIM, H_DIM, 1);
    // h2 partials = h1 @ W2, MFMA split-K=4 (chunk 768, lda=3072), no bias
    gemm_mfma_kernel<<<dim3(H_DIM / 128, BE / 128, 4), 256, 0, stream>>>(
        h1, W2, nullptr, h2p, BE, H_DIM, INTER / 4, INTER, 0);

    // layernorm( sum partials + b2 ) -> out[0..393215], loss -> out[393216]
    ln_kernel<<<BE, 256, 0, stream>>>(h2p, b2, ln_g, ln_b, out);
    write_loss_kernel<<<1, 64, 0, stream>>>(loss, out + (size_t)BE * H_DIM);
}